// Round 21
// baseline (126.258 us; speedup 1.0000x reference)
//
#include <hip/hip_runtime.h>
#include <hip/hip_cooperative_groups.h>
#include <math.h>

namespace cg = cooperative_groups;

// Problem constants: L=16384, H=256, P=512.
#define L_SEQ 16384
#define H_DIM 256
#define P_DIM 512
#define CL 64                 // chunk length == per-block row strip
#define NC (L_SEQ / CL)       // 256 chunks == 256 blocks (1/CU, co-resident)

typedef __attribute__((ext_vector_type(8))) short bf16x8;
typedef __attribute__((ext_vector_type(4))) float f32x4;

static __device__ __forceinline__ unsigned short f2bf(float f) {
  unsigned int u = __builtin_bit_cast(unsigned int, f);
  u += 0x7FFFu + ((u >> 16) & 1u);
  return (unsigned short)(u >> 16);
}
static __device__ __forceinline__ float bflo(unsigned int v) {
  return __builtin_bit_cast(float, v << 16);
}
static __device__ __forceinline__ float bfhi(unsigned int v) {
  return __builtin_bit_cast(float, v & 0xFFFF0000u);
}
static __device__ __forceinline__ float bf2f(unsigned short s) {
  return __builtin_bit_cast(float, (unsigned int)s << 16);
}
static __device__ __forceinline__ unsigned int pack2(float r, float i) {
  return (unsigned int)f2bf(r) | ((unsigned int)f2bf(i) << 16);
}
// ys-LDS seg-XOR swizzle (16B segs, seg ^= row&15) — used by ALL accessors.
static __device__ __forceinline__ int swz_n(int row, int n) {
  int seg = n >> 3;
  seg = (seg & 0x70) | ((seg ^ row) & 0x0F);
  return seg * 8 + (n & 7);
}

// Weights K-PACKED: unit = (k>>3)*N + n, element = unit*8 + (k&7).
// prep branches: [0,2): params (Mc=M^64) + a/b tables (row2 of M^{t+1}, t=0..63);
// [2,1026): W1b; [1026,2050): W2b; [2050,6146): cast u->ub.
__global__ __launch_bounds__(256) void prep_all(
    const float* __restrict__ A_diag, const float* __restrict__ G_diag,
    const float* __restrict__ dt, const float* __restrict__ B,
    const float* __restrict__ C, const float* __restrict__ u,
    float* __restrict__ prm, unsigned short* __restrict__ W1b,
    unsigned short* __restrict__ W2b, unsigned short* __restrict__ ub,
    float* __restrict__ aT, float* __restrict__ bT) {
  const int b = blockIdx.x;
  const int t = threadIdx.x;
  if (b < 2) {
    int p = b * 256 + t;
    float dts = 1.0f / (1.0f + expf(-dt[p]));
    float G = fmaxf(G_diag[p], 0.0f);
    float g = dts * G;
    float root = sqrtf(1.0f - g);
    float denom = fmaxf(dts * dts, 1e-6f);
    float A_low  = (2.0f - g - 2.0f * root) / denom;
    float A_high = (2.0f - g + 2.0f * root) / denom;
    float Ad = A_diag[p];
    float A = A_low + fmaxf(Ad - A_low, 0.0f) - fmaxf(Ad - A_high, 0.0f);
    float m00 = 1.0f - g;
    float m01 = -dts * A;
    float m10 = dts * (1.0f - g);
    float m11 = 1.0f - dts * dts * A;
    // a/b tables: cur = M^{t+1}, store row 2; cur = M*cur   (t = 0..63)
    float e00 = m00, e01 = m01, e10 = m10, e11 = m11;
    for (int s = 0; s < 64; s++) {
      aT[s * P_DIM + p] = e10;
      bT[s * P_DIM + p] = e11;
      float f00 = m00 * e00 + m01 * e10;
      float f01 = m00 * e01 + m01 * e11;
      float f10 = m10 * e00 + m11 * e10;
      float f11 = m10 * e01 + m11 * e11;
      e00 = f00; e01 = f01; e10 = f10; e11 = f11;
    }
    // Mc = M^64 (6 squarings); rho(M)<=1 by construction
    float c00 = m00, c01 = m01, c10 = m10, c11 = m11;
#pragma unroll
    for (int i = 0; i < 6; i++) {
      float n00 = c00 * c00 + c01 * c10;
      float n01 = c00 * c01 + c01 * c11;
      float n10 = c10 * c00 + c11 * c10;
      float n11 = c10 * c01 + c11 * c11;
      c00 = n00; c01 = n01; c10 = n10; c11 = n11;
    }
    prm[0 * P_DIM + p] = m00;
    prm[1 * P_DIM + p] = m01;
    prm[2 * P_DIM + p] = m10;
    prm[3 * P_DIM + p] = m11;
    prm[4 * P_DIM + p] = dts;
    prm[5 * P_DIM + p] = dts * dts;
    prm[6 * P_DIM + p] = c00;
    prm[7 * P_DIM + p] = c01;
    prm[8 * P_DIM + p] = c10;
    prm[9 * P_DIM + p] = c11;
  } else if (b < 2 + 1024) {
    int idx = (b - 2) * 256 + t;          // n=2p+c in [0,1024), k=h in [0,256)
    int n = idx >> 8;
    int k = idx & 255;
    int p = n >> 1, c = n & 1;
    W1b[((size_t)(k >> 3) * 1024 + n) * 8 + (k & 7)] = f2bf(B[(p * H_DIM + k) * 2 + c]);
  } else if (b < 2 + 2048) {
    int idx = (b - 1026) * 256 + t;       // n=h in [0,256), k=2p+c in [0,1024)
    int h = idx >> 10;
    int k = idx & 1023;
    int p = k >> 1, c = k & 1;
    float v = C[(h * P_DIM + p) * 2 + c];
    W2b[((size_t)(k >> 3) * 256 + h) * 8 + (k & 7)] = f2bf(c ? -v : v);
  } else {
    int idx = (b - 2050) * 256 + t;       // cast u
    float4 v = ((const float4*)u)[idx];
    ushort4 o;
    o.x = f2bf(v.x); o.y = f2bf(v.y); o.z = f2bf(v.z); o.w = f2bf(v.w);
    ((ushort4*)ub)[idx] = o;
  }
}

// Cooperative megakernel: 256 blocks x 512 threads (8 waves, 1 block/CU).
// LDS 136KB: ys slice [64][1024] bf16 swizzled (131072B) + 8KB scan scratch.
// Phase A: GEMM1 (64x1024, K=256) barrier-free, C -> ys LDS; in-LDS local scan
//          OVERWRITES ysl with ys_local = x2 per step (R20 bug: was missing) -> finals.
// grid.sync. Phase B: Hillis-Steele carry over 256 chunks (2 p's per block).
// grid.sync. Phase C: in-LDS carry correction; GEMM2 (64x256, K=1024) barrier-free -> out.
__global__ __launch_bounds__(512) void mega(
    const unsigned short* __restrict__ ub, const unsigned short* __restrict__ W1b,
    const unsigned short* __restrict__ W2b, const float* __restrict__ prm,
    const float* __restrict__ aT, const float* __restrict__ bT,
    const float* __restrict__ Dv, float4* __restrict__ finals,
    float4* __restrict__ carry, float* __restrict__ out) {
  extern __shared__ char smem[];
  unsigned short* ysl = (unsigned short*)smem;          // [64][1024] swizzled
  float4* sb = (float4*)(smem + 131072);                // 2 x 256 float4 (phase B)

  cg::grid_group grid = cg::this_grid();
  const int tid = threadIdx.x;
  const int lane = tid & 63;
  const int wid = tid >> 6;          // 0..7
  const int blk = blockIdx.x;        // owns rows [blk*64, +64) == chunk blk
  const int bm = blk * 64;
  const int rA = lane & 15;
  const int g  = lane >> 4;
  const int wr = wid & 1;            // row half (32 rows)
  const int wq = wid >> 1;           // col quarter (64 cols)
  const int cr = g * 4;
  const int cc = rA;

  // ---- Phase A: GEMM1, barrier-free (af: ub L1-hot; wf: W1b k-packed L2-hot)
  for (int nch = 0; nch < 4; nch++) {
    const int nc0 = nch * 256 + wq * 64;
    f32x4 acc[2][4] = {};
    for (int k0 = 0; k0 < 256; k0 += 32) {
      bf16x8 af[2], wf[4];
#pragma unroll
      for (int m = 0; m < 2; m++) {
        const int row = bm + wr * 32 + m * 16 + rA;
        af[m] = *(const bf16x8*)&ub[(size_t)row * 256 + k0 + g * 8];
      }
#pragma unroll
      for (int j = 0; j < 4; j++) {
        const int n = nc0 + j * 16 + rA;
        wf[j] = *(const bf16x8*)&W1b[(((size_t)(k0 >> 3) + g) * 1024 + n) * 8];
      }
#pragma unroll
      for (int m = 0; m < 2; m++)
#pragma unroll
        for (int j = 0; j < 4; j++)
          acc[m][j] = __builtin_amdgcn_mfma_f32_16x16x32_bf16(af[m], wf[j], acc[m][j], 0, 0, 0);
    }
    // C -> ys LDS (bf16 shorts, swizzled). C/D: col=lane&15, row=(lane>>4)*4+q.
#pragma unroll
    for (int m = 0; m < 2; m++)
#pragma unroll
      for (int j = 0; j < 4; j++) {
        const int rl = wr * 32 + m * 16 + cr;
        const int n = nc0 + j * 16 + cc;
#pragma unroll
        for (int q = 0; q < 4; q++)
          ysl[(rl + q) * 1024 + swz_n(rl + q, n)] = f2bf(acc[m][j][q]);
      }
  }
  __syncthreads();

  // ---- local scan: thread p scans its column over 64 rows, OVERWRITING each
  // Bu entry with ys_local = x2 (the value Phase C corrects). In-place safe:
  // thread owns its column.
  {
    const int p = tid;
    float m00 = prm[0 * P_DIM + p], m01 = prm[1 * P_DIM + p];
    float m10 = prm[2 * P_DIM + p], m11 = prm[3 * P_DIM + p];
    float dts = prm[4 * P_DIM + p], dts2 = prm[5 * P_DIM + p];
    float x1r = 0.f, x2r = 0.f, x1i = 0.f, x2i = 0.f;
    for (int row = 0; row < 64; row++) {
      unsigned int* addr = (unsigned int*)&ysl[row * 1024 + swz_n(row, 2 * p)];
      unsigned int v = *addr;
      float bx = bflo(v), by = bfhi(v);
      float n1r = fmaf(m00, x1r, fmaf(m01, x2r, dts * bx));
      float n2r = fmaf(m10, x1r, fmaf(m11, x2r, dts2 * bx));
      float n1i = fmaf(m00, x1i, fmaf(m01, x2i, dts * by));
      float n2i = fmaf(m10, x1i, fmaf(m11, x2i, dts2 * by));
      *addr = pack2(n2r, n2i);          // ys_local write-back (the R20 fix)
      x1r = n1r; x2r = n2r; x1i = n1i; x2i = n2i;
    }
    finals[(size_t)blk * P_DIM + p] = make_float4(x1r, x2r, x1i, x2i);
  }
  grid.sync();

  // ---- Phase B: Hillis-Steele over NC=256 chunks; block handles p = 2*blk, 2*blk+1
  {
    const int pp = tid >> 8;           // 0,1
    const int c = tid & 255;
    const int p = blk * 2 + pp;
    float m00 = prm[6 * P_DIM + p], m01 = prm[7 * P_DIM + p];
    float m10 = prm[8 * P_DIM + p], m11 = prm[9 * P_DIM + p];
    float4 b4 = finals[(size_t)c * P_DIM + p];
    float4* sbp = sb + pp * 256;
    for (int o = 1; o < NC; o <<= 1) {
      sbp[c] = b4;
      __syncthreads();
      float4 nb = (c >= o) ? sbp[c - o] : make_float4(0.f, 0.f, 0.f, 0.f);
      __syncthreads();
      b4.x = fmaf(m00, nb.x, fmaf(m01, nb.y, b4.x));
      b4.y = fmaf(m10, nb.x, fmaf(m11, nb.y, b4.y));
      b4.z = fmaf(m00, nb.z, fmaf(m01, nb.w, b4.z));
      b4.w = fmaf(m10, nb.z, fmaf(m11, nb.w, b4.w));
      float n00 = m00 * m00 + m01 * m10;
      float n01 = m00 * m01 + m01 * m11;
      float n10 = m10 * m00 + m11 * m10;
      float n11 = m10 * m01 + m11 * m11;
      m00 = n00; m01 = n01; m10 = n10; m11 = n11;
    }
    if (c + 1 < NC) carry[(size_t)(c + 1) * P_DIM + p] = b4;
    if (c == 0) carry[p] = make_float4(0.f, 0.f, 0.f, 0.f);
  }
  grid.sync();

  // ---- Phase C: in-LDS carry correction (thread p, 64 rows)
  {
    const int p = tid;
    float4 x = carry[(size_t)blk * P_DIM + p];
    for (int row = 0; row < 64; row++) {
      float a = aT[row * P_DIM + p];
      float b = bT[row * P_DIM + p];
      unsigned int* addr = (unsigned int*)&ysl[row * 1024 + swz_n(row, 2 * p)];
      unsigned int v = *addr;
      *addr = pack2(bflo(v) + a * x.x + b * x.y, bfhi(v) + a * x.z + b * x.w);
    }
  }
  __syncthreads();

  // ---- GEMM2: out[64x256] = ys(LDS) @ W2b^T + ub*D, barrier-free
  {
    f32x4 acc[2][4] = {};
    for (int k0 = 0; k0 < 1024; k0 += 32) {
      bf16x8 af[2], wf[4];
#pragma unroll
      for (int m = 0; m < 2; m++) {
        const int row = wr * 32 + m * 16 + rA;
        af[m] = *(const bf16x8*)&ysl[row * 1024 + swz_n(row, k0 + g * 8)];
      }
#pragma unroll
      for (int j = 0; j < 4; j++) {
        const int col = wq * 64 + j * 16 + rA;
        wf[j] = *(const bf16x8*)&W2b[(((size_t)(k0 >> 3) + g) * 256 + col) * 8];
      }
#pragma unroll
      for (int m = 0; m < 2; m++)
#pragma unroll
        for (int j = 0; j < 4; j++)
          acc[m][j] = __builtin_amdgcn_mfma_f32_16x16x32_bf16(af[m], wf[j], acc[m][j], 0, 0, 0);
    }
#pragma unroll
    for (int m = 0; m < 2; m++)
#pragma unroll
      for (int j = 0; j < 4; j++) {
        const int col = wq * 64 + j * 16 + cc;
        const float d = Dv[col];
#pragma unroll
        for (int q = 0; q < 4; q++) {
          const int row = bm + wr * 32 + m * 16 + cr + q;
          const size_t idx = (size_t)row * H_DIM + col;
          out[idx] = fmaf(bf2f(ub[idx]), d, acc[m][j][q]);
        }
      }
  }
}

extern "C" void kernel_launch(void* const* d_in, const int* in_sizes, int n_in,
                              void* d_out, int out_size, void* d_ws, size_t ws_size,
                              hipStream_t stream) {
  const float* u      = (const float*)d_in[0];  // (L, H)
  const float* A_diag = (const float*)d_in[1];
  const float* G_diag = (const float*)d_in[2];
  const float* dt     = (const float*)d_in[3];
  const float* B      = (const float*)d_in[4];  // (P, H, 2)
  const float* C      = (const float*)d_in[5];  // (H, P, 2)
  const float* D      = (const float*)d_in[6];  // (H,)
  float* out = (float*)d_out;

  // Workspace (~14MB): ub 8.4MB | W1b 0.5 | W2b 0.5 | prm | finals 2MB | carry 2MB | aT/bT 256KB
  char* w = (char*)d_ws;
  unsigned short* ub  = (unsigned short*)w;                         // L*256 bf16
  unsigned short* W1b = ub + (size_t)L_SEQ * H_DIM;                 // k-packed
  unsigned short* W2b = W1b + 1024 * H_DIM;                         // k-packed
  float* prm    = (float*)(W2b + H_DIM * 1024);                     // 10*512 (pad 8192)
  float* finals = prm + 8192;                                       // NC*P*4
  float* carryb = finals + (size_t)NC * P_DIM * 4;                  // NC*P*4
  float* aT     = carryb + (size_t)NC * P_DIM * 4;                  // 64*512
  float* bT     = aT + 64 * P_DIM;                                  // 64*512

  prep_all<<<2 + 1024 + 1024 + 4096, 256, 0, stream>>>(
      A_diag, G_diag, dt, B, C, u, prm, W1b, W2b, ub, aT, bT);

  // Cooperative megakernel: 256 blocks x 512 threads, 136KB dynamic LDS
  void* args[] = {
      (void*)&ub, (void*)&W1b, (void*)&W2b, (void*)&prm,
      (void*)&aT, (void*)&bT, (void*)&D, (void*)&finals,
      (void*)&carryb, (void*)&out};
  hipLaunchCooperativeKernel((const void*)mega, dim3(NC), dim3(512), args,
                             131072 + 8192, stream);
}